// Round 2
// baseline (681.925 us; speedup 1.0000x reference)
//
#include <hip/hip_runtime.h>
#include <hip/hip_bf16.h>

typedef __attribute__((ext_vector_type(4))) float f32x4;
typedef __attribute__((ext_vector_type(4))) float fv4;
typedef __attribute__((ext_vector_type(8))) short bf16x8;
typedef __attribute__((ext_vector_type(4))) short bf16x4;

#define DEVI __device__ __forceinline__

constexpr int BATCH = 4, SEQ = 1024, NH = 16, HD = 64, DM_ = 1024;
constexpr int NTOK = BATCH * SEQ;  // 4096

DEVI unsigned short f2bf(float f) {
  union { float f; unsigned u; } v; v.f = f;
  unsigned r = v.u + 0x7FFFu + ((v.u >> 16) & 1u);  // RNE
  return (unsigned short)(r >> 16);
}

// XOR-swizzled element offset within a [rows][64] bf16 LDS tile (16B granules).
DEVI int swz64(int row, int col) {
  int byte = (row * 64 + col) * 2;
  byte ^= (row & 7) << 4;
  return byte >> 1;
}

// ---------------------------------------------------------------------------
// K1: fused QKV projection.  Y = X @ W^T + b, output bf16.
//   z=0: q (prescaled by 1/8), z=1: k, z=2: v stored transposed [b*1024+o][s]
// ---------------------------------------------------------------------------
__global__ __launch_bounds__(256) void k_proj(
    const float* __restrict__ Xq, const float* __restrict__ Xk,
    const float* __restrict__ Xv,
    const float* __restrict__ Wq, const float* __restrict__ Wk,
    const float* __restrict__ Wv,
    const float* __restrict__ bq, const float* __restrict__ bk,
    const float* __restrict__ bv,
    unsigned short* __restrict__ qo, unsigned short* __restrict__ ko,
    unsigned short* __restrict__ vTo)
{
  const int z = blockIdx.z;
  const float* X = (z == 0) ? Xq : (z == 1) ? Xk : Xv;
  const float* W = (z == 0) ? Wq : (z == 1) ? Wk : Wv;
  const float* bias = (z == 0) ? bq : (z == 1) ? bk : bv;

  __shared__ __align__(16) unsigned short Al[128 * 64];
  __shared__ __align__(16) unsigned short Bl[128 * 64];

  const int tid = threadIdx.x;
  const int lane = tid & 63;
  const int w = tid >> 6;
  const int wm = w & 1, wn = w >> 1;
  const int l15 = lane & 15, lg = lane >> 4;
  const int m0 = blockIdx.x * 128;  // token rows
  const int o0 = blockIdx.y * 128;  // output cols

  f32x4 acc[4][4];
#pragma unroll
  for (int i = 0; i < 4; ++i)
#pragma unroll
    for (int j = 0; j < 4; ++j) acc[i][j] = f32x4{0.f, 0.f, 0.f, 0.f};

  const int srow = tid >> 3;        // 0..31
  const int scol = (tid & 7) * 8;   // 0..56

  for (int kt = 0; kt < 16; ++kt) {
    const int k0 = kt * 64;
    __syncthreads();
#pragma unroll
    for (int p = 0; p < 4; ++p) {
      const int r = p * 32 + srow;
      {
        const float* sa = X + (size_t)(m0 + r) * DM_ + k0 + scol;
        fv4 a0 = *(const fv4*)sa;
        fv4 a1 = *(const fv4*)(sa + 4);
        bf16x8 ha;
        ha[0] = (short)f2bf(a0[0]); ha[1] = (short)f2bf(a0[1]);
        ha[2] = (short)f2bf(a0[2]); ha[3] = (short)f2bf(a0[3]);
        ha[4] = (short)f2bf(a1[0]); ha[5] = (short)f2bf(a1[1]);
        ha[6] = (short)f2bf(a1[2]); ha[7] = (short)f2bf(a1[3]);
        *(bf16x8*)&Al[swz64(r, scol)] = ha;
      }
      {
        const float* sb = W + (size_t)(o0 + r) * DM_ + k0 + scol;
        fv4 b0 = *(const fv4*)sb;
        fv4 b1 = *(const fv4*)(sb + 4);
        bf16x8 hb;
        hb[0] = (short)f2bf(b0[0]); hb[1] = (short)f2bf(b0[1]);
        hb[2] = (short)f2bf(b0[2]); hb[3] = (short)f2bf(b0[3]);
        hb[4] = (short)f2bf(b1[0]); hb[5] = (short)f2bf(b1[1]);
        hb[6] = (short)f2bf(b1[2]); hb[7] = (short)f2bf(b1[3]);
        *(bf16x8*)&Bl[swz64(r, scol)] = hb;
      }
    }
    __syncthreads();
#pragma unroll
    for (int kk = 0; kk < 2; ++kk) {
      bf16x8 af[4], bfm[4];
#pragma unroll
      for (int m = 0; m < 4; ++m)
        af[m] = *(const bf16x8*)&Al[swz64(wm * 64 + m * 16 + l15, kk * 32 + lg * 8)];
#pragma unroll
      for (int n = 0; n < 4; ++n)
        bfm[n] = *(const bf16x8*)&Bl[swz64(wn * 64 + n * 16 + l15, kk * 32 + lg * 8)];
#pragma unroll
      for (int m = 0; m < 4; ++m)
#pragma unroll
        for (int n = 0; n < 4; ++n)
          acc[m][n] = __builtin_amdgcn_mfma_f32_16x16x32_bf16(af[m], bfm[n], acc[m][n], 0, 0, 0);
    }
  }

#pragma unroll
  for (int n = 0; n < 4; ++n) {
    const int oc = o0 + wn * 64 + n * 16 + l15;
    const float bb = bias[oc];
#pragma unroll
    for (int m = 0; m < 4; ++m) {
      const int rbase = m0 + wm * 64 + m * 16 + lg * 4;
      if (z == 2) {
        bf16x4 pv;
#pragma unroll
        for (int j = 0; j < 4; ++j) pv[j] = (short)f2bf(acc[m][n][j] + bb);
        // vT[(b*1024 + o)][s], 4 consecutive s per lane
        *(bf16x4*)&vTo[((size_t)(rbase >> 10) * 1024 + oc) * 1024 + (rbase & 1023)] = pv;
      } else {
        unsigned short* Y = (z == 0) ? qo : ko;
        const float sc = (z == 0) ? 0.125f : 1.f;  // fold 1/sqrt(DK) into q
#pragma unroll
        for (int j = 0; j < 4; ++j)
          Y[(size_t)(rbase + j) * DM_ + oc] = f2bf((acc[m][n][j] + bb) * sc);
      }
    }
  }
}

// ---------------------------------------------------------------------------
// K2: scores + mask + softmax, writes attn (f32) to d_out attn region.
// Block = 16 q-rows x full 1024 k. 4 waves, each owns a 256-wide k slice
// (interleaved by 64). Scores live in MFMA accumulators only.
// ---------------------------------------------------------------------------
__global__ __launch_bounds__(256) void k_attn(
    const unsigned short* __restrict__ qb, const unsigned short* __restrict__ kb,
    const int* __restrict__ mask, float* __restrict__ attn)
{
  const int tid = threadIdx.x;
  const int lane = tid & 63;
  const int w = tid >> 6;
  const int l15 = lane & 15, lg = lane >> 4;
  const int hb = blockIdx.y;            // h*B + b
  const int h = hb >> 2, b = hb & 3;
  const int q0 = blockIdx.x * 16;
  const int qrow = lg * 4;              // row group within 16

  bf16x8 aq0, aq1;
  {
    const unsigned short* qp =
        qb + (size_t)(b * SEQ + q0 + l15) * DM_ + h * HD + lg * 8;
    aq0 = *(const bf16x8*)qp;
    aq1 = *(const bf16x8*)(qp + 32);
  }
  int qm[4];
#pragma unroll
  for (int j = 0; j < 4; ++j) qm[j] = mask[b * SEQ + q0 + qrow + j];

  f32x4 acc[16];
#pragma unroll
  for (int f = 0; f < 16; ++f) acc[f] = f32x4{0.f, 0.f, 0.f, 0.f};

#pragma unroll
  for (int f = 0; f < 16; ++f) {
    const int krow = (f >> 2) * 256 + w * 64 + (f & 3) * 16 + l15;
    const unsigned short* kp =
        kb + (size_t)(b * SEQ + krow) * DM_ + h * HD + lg * 8;
    bf16x8 b0 = *(const bf16x8*)kp;
    bf16x8 b1 = *(const bf16x8*)(kp + 32);
    acc[f] = __builtin_amdgcn_mfma_f32_16x16x32_bf16(aq0, b0, acc[f], 0, 0, 0);
    acc[f] = __builtin_amdgcn_mfma_f32_16x16x32_bf16(aq1, b1, acc[f], 0, 0, 0);
  }

  unsigned kv = 0;
#pragma unroll
  for (int f = 0; f < 16; ++f) {
    const int krow = (f >> 2) * 256 + w * 64 + (f & 3) * 16 + l15;
    if (mask[b * SEQ + krow] == 0) kv |= (1u << f);
  }

  // pass 1: row max over valid entries
  float rmax[4] = {-1e30f, -1e30f, -1e30f, -1e30f};
#pragma unroll
  for (int f = 0; f < 16; ++f) {
    const int krow = (f >> 2) * 256 + w * 64 + (f & 3) * 16 + l15;
#pragma unroll
    for (int j = 0; j < 4; ++j) {
      const bool vld = ((kv >> f) & 1u) && (qm[j] == 0) && (krow <= q0 + qrow + j);
      if (vld) rmax[j] = fmaxf(rmax[j], acc[f][j]);
    }
  }
#pragma unroll
  for (int j = 0; j < 4; ++j) {
    rmax[j] = fmaxf(rmax[j], __shfl_xor(rmax[j], 1, 64));
    rmax[j] = fmaxf(rmax[j], __shfl_xor(rmax[j], 2, 64));
    rmax[j] = fmaxf(rmax[j], __shfl_xor(rmax[j], 4, 64));
    rmax[j] = fmaxf(rmax[j], __shfl_xor(rmax[j], 8, 64));
  }

  __shared__ float red[2][4][16];
  if (l15 == 0) {
#pragma unroll
    for (int j = 0; j < 4; ++j) red[0][w][qrow + j] = rmax[j];
  }
  __syncthreads();
#pragma unroll
  for (int j = 0; j < 4; ++j)
    rmax[j] = fmaxf(fmaxf(red[0][0][qrow + j], red[0][1][qrow + j]),
                    fmaxf(red[0][2][qrow + j], red[0][3][qrow + j]));

  // pass 2: exp + row sum (overwrite acc with p)
  float rsum[4] = {0.f, 0.f, 0.f, 0.f};
#pragma unroll
  for (int f = 0; f < 16; ++f) {
    const int krow = (f >> 2) * 256 + w * 64 + (f & 3) * 16 + l15;
#pragma unroll
    for (int j = 0; j < 4; ++j) {
      const bool vld = ((kv >> f) & 1u) && (qm[j] == 0) && (krow <= q0 + qrow + j);
      const float p = vld ? __expf(acc[f][j] - rmax[j]) : 0.f;
      acc[f][j] = p;
      rsum[j] += p;
    }
  }
#pragma unroll
  for (int j = 0; j < 4; ++j) {
    rsum[j] += __shfl_xor(rsum[j], 1, 64);
    rsum[j] += __shfl_xor(rsum[j], 2, 64);
    rsum[j] += __shfl_xor(rsum[j], 4, 64);
    rsum[j] += __shfl_xor(rsum[j], 8, 64);
  }
  if (l15 == 0) {
#pragma unroll
    for (int j = 0; j < 4; ++j) red[1][w][qrow + j] = rsum[j];
  }
  __syncthreads();
  float rinv[4];
#pragma unroll
  for (int j = 0; j < 4; ++j) {
    const float s = red[1][0][qrow + j] + red[1][1][qrow + j] +
                    red[1][2][qrow + j] + red[1][3][qrow + j];
    rinv[j] = (s > 0.f) ? (1.f / s) : 0.f;  // fully-masked row -> zeros
  }

  float* ap = attn + (size_t)hb * SEQ * SEQ;
#pragma unroll
  for (int f = 0; f < 16; ++f) {
    const int krow = (f >> 2) * 256 + w * 64 + (f & 3) * 16 + l15;
#pragma unroll
    for (int j = 0; j < 4; ++j)
      ap[(size_t)(q0 + qrow + j) * SEQ + krow] = acc[f][j] * rinv[j];
  }
}

// ---------------------------------------------------------------------------
// K3: O = attn @ V  (per head-batch).  attn re-read f32 from d_out, V from
// transposed bf16 ws (B^T layout -> contiguous ds_read_b128 fragments).
// ---------------------------------------------------------------------------
__global__ __launch_bounds__(256) void k_pv(
    const float* __restrict__ attn, const unsigned short* __restrict__ vT,
    unsigned short* __restrict__ Ob)
{
  const int tid = threadIdx.x;
  const int lane = tid & 63;
  const int w = tid >> 6;
  const int wm = w & 1, wn = w >> 1;
  const int l15 = lane & 15, lg = lane >> 4;
  const int hb = blockIdx.y, h = hb >> 2, b = hb & 3;
  const int q0 = blockIdx.x * 128;

  __shared__ __align__(16) unsigned short Pl[128 * 64];
  __shared__ __align__(16) unsigned short Vl[64 * 64];

  const float* ap = attn + (size_t)hb * SEQ * SEQ;
  const unsigned short* vp = vT + ((size_t)b * 1024 + h * 64) * 1024;

  f32x4 acc[4][2];
#pragma unroll
  for (int m = 0; m < 4; ++m) {
    acc[m][0] = f32x4{0.f, 0.f, 0.f, 0.f};
    acc[m][1] = f32x4{0.f, 0.f, 0.f, 0.f};
  }

  const int prow = tid >> 3, pcol = (tid & 7) * 8;
  const int vrow = tid >> 2, vcol = (tid & 3) * 16;

  for (int kt = 0; kt < 16; ++kt) {
    const int k0 = kt * 64;
    __syncthreads();
#pragma unroll
    for (int p = 0; p < 4; ++p) {
      const int r = p * 32 + prow;
      const float* src = ap + (size_t)(q0 + r) * SEQ + k0 + pcol;
      fv4 a0 = *(const fv4*)src;
      fv4 a1 = *(const fv4*)(src + 4);
      bf16x8 hv;
      hv[0] = (short)f2bf(a0[0]); hv[1] = (short)f2bf(a0[1]);
      hv[2] = (short)f2bf(a0[2]); hv[3] = (short)f2bf(a0[3]);
      hv[4] = (short)f2bf(a1[0]); hv[5] = (short)f2bf(a1[1]);
      hv[6] = (short)f2bf(a1[2]); hv[7] = (short)f2bf(a1[3]);
      *(bf16x8*)&Pl[swz64(r, pcol)] = hv;
    }
    {
      const unsigned short* src = vp + (size_t)vrow * 1024 + k0 + vcol;
      *(bf16x8*)&Vl[swz64(vrow, vcol)] = *(const bf16x8*)src;
      *(bf16x8*)&Vl[swz64(vrow, vcol + 8)] = *(const bf16x8*)(src + 8);
    }
    __syncthreads();
#pragma unroll
    for (int kk = 0; kk < 2; ++kk) {
      bf16x8 af[4], bfm[2];
#pragma unroll
      for (int m = 0; m < 4; ++m)
        af[m] = *(const bf16x8*)&Pl[swz64(wm * 64 + m * 16 + l15, kk * 32 + lg * 8)];
#pragma unroll
      for (int n = 0; n < 2; ++n)
        bfm[n] = *(const bf16x8*)&Vl[swz64(wn * 32 + n * 16 + l15, kk * 32 + lg * 8)];
#pragma unroll
      for (int m = 0; m < 4; ++m)
#pragma unroll
        for (int n = 0; n < 2; ++n)
          acc[m][n] = __builtin_amdgcn_mfma_f32_16x16x32_bf16(af[m], bfm[n], acc[m][n], 0, 0, 0);
    }
  }

#pragma unroll
  for (int n = 0; n < 2; ++n) {
    const int d = wn * 32 + n * 16 + l15;
#pragma unroll
    for (int m = 0; m < 4; ++m) {
      const int rbase = q0 + wm * 64 + m * 16 + lg * 4;
#pragma unroll
      for (int j = 0; j < 4; ++j)
        Ob[(size_t)(b * SEQ + rbase + j) * DM_ + h * 64 + d] = f2bf(acc[m][n][j]);
    }
  }
}

// ---------------------------------------------------------------------------
// K4: preLN = O @ Wo^T + bo + query   (residual folded in epilogue)
// ---------------------------------------------------------------------------
__global__ __launch_bounds__(256) void k_oproj(
    const unsigned short* __restrict__ Ob, const float* __restrict__ Wo,
    const float* __restrict__ bo, const float* __restrict__ query,
    float* __restrict__ preln)
{
  const int tid = threadIdx.x;
  const int lane = tid & 63;
  const int w = tid >> 6;
  const int wm = w & 1, wn = w >> 1;
  const int l15 = lane & 15, lg = lane >> 4;
  const int m0 = blockIdx.x * 128;
  const int o0 = blockIdx.y * 128;

  __shared__ __align__(16) unsigned short Al[128 * 64];
  __shared__ __align__(16) unsigned short Bl[128 * 64];

  f32x4 acc[4][4];
#pragma unroll
  for (int i = 0; i < 4; ++i)
#pragma unroll
    for (int j = 0; j < 4; ++j) acc[i][j] = f32x4{0.f, 0.f, 0.f, 0.f};

  const int arow = tid >> 2, acol = (tid & 3) * 16;
  const int brow = tid >> 3, bcol = (tid & 7) * 8;

  for (int kt = 0; kt < 16; ++kt) {
    const int k0 = kt * 64;
    __syncthreads();
#pragma unroll
    for (int p = 0; p < 2; ++p) {
      const int r = p * 64 + arow;
      const unsigned short* src = Ob + (size_t)(m0 + r) * DM_ + k0 + acol;
      *(bf16x8*)&Al[swz64(r, acol)] = *(const bf16x8*)src;
      *(bf16x8*)&Al[swz64(r, acol + 8)] = *(const bf16x8*)(src + 8);
    }
#pragma unroll
    for (int p = 0; p < 4; ++p) {
      const int r = p * 32 + brow;
      const float* sb = Wo + (size_t)(o0 + r) * DM_ + k0 + bcol;
      fv4 b0 = *(const fv4*)sb;
      fv4 b1 = *(const fv4*)(sb + 4);
      bf16x8 hb;
      hb[0] = (short)f2bf(b0[0]); hb[1] = (short)f2bf(b0[1]);
      hb[2] = (short)f2bf(b0[2]); hb[3] = (short)f2bf(b0[3]);
      hb[4] = (short)f2bf(b1[0]); hb[5] = (short)f2bf(b1[1]);
      hb[6] = (short)f2bf(b1[2]); hb[7] = (short)f2bf(b1[3]);
      *(bf16x8*)&Bl[swz64(r, bcol)] = hb;
    }
    __syncthreads();
#pragma unroll
    for (int kk = 0; kk < 2; ++kk) {
      bf16x8 af[4], bfm[4];
#pragma unroll
      for (int m = 0; m < 4; ++m)
        af[m] = *(const bf16x8*)&Al[swz64(wm * 64 + m * 16 + l15, kk * 32 + lg * 8)];
#pragma unroll
      for (int n = 0; n < 4; ++n)
        bfm[n] = *(const bf16x8*)&Bl[swz64(wn * 64 + n * 16 + l15, kk * 32 + lg * 8)];
#pragma unroll
      for (int m = 0; m < 4; ++m)
#pragma unroll
        for (int n = 0; n < 4; ++n)
          acc[m][n] = __builtin_amdgcn_mfma_f32_16x16x32_bf16(af[m], bfm[n], acc[m][n], 0, 0, 0);
    }
  }

#pragma unroll
  for (int n = 0; n < 4; ++n) {
    const int oc = o0 + wn * 64 + n * 16 + l15;
    const float bb = bo[oc];
#pragma unroll
    for (int m = 0; m < 4; ++m) {
      const int rbase = m0 + wm * 64 + m * 16 + lg * 4;
#pragma unroll
      for (int j = 0; j < 4; ++j) {
        const size_t idx = (size_t)(rbase + j) * DM_ + oc;
        preln[idx] = acc[m][n][j] + bb + query[idx];
      }
    }
  }
}

// ---------------------------------------------------------------------------
// K5: LayerNorm over DM=1024, one block per row.
// ---------------------------------------------------------------------------
__global__ __launch_bounds__(256) void k_ln(
    const float* __restrict__ x, const float* __restrict__ g,
    const float* __restrict__ bta, float* __restrict__ out)
{
  const int row = blockIdx.x;
  const int tid = threadIdx.x;
  const float* xr = x + (size_t)row * DM_;
  fv4 v = *(const fv4*)(xr + tid * 4);
  float s = v[0] + v[1] + v[2] + v[3];
  float s2 = v[0] * v[0] + v[1] * v[1] + v[2] * v[2] + v[3] * v[3];
#pragma unroll
  for (int off = 1; off < 64; off <<= 1) {
    s += __shfl_xor(s, off, 64);
    s2 += __shfl_xor(s2, off, 64);
  }
  __shared__ float rs[2][4];
  const int w = tid >> 6;
  if ((tid & 63) == 0) { rs[0][w] = s; rs[1][w] = s2; }
  __syncthreads();
  s = rs[0][0] + rs[0][1] + rs[0][2] + rs[0][3];
  s2 = rs[1][0] + rs[1][1] + rs[1][2] + rs[1][3];
  const float mu = s * (1.f / 1024.f);
  const float var = s2 * (1.f / 1024.f) - mu * mu;
  const float rstd = rsqrtf(var + 1e-12f);
  fv4 gg = *(const fv4*)(g + tid * 4);
  fv4 bb = *(const fv4*)(bta + tid * 4);
  fv4 o;
#pragma unroll
  for (int j = 0; j < 4; ++j) o[j] = (v[j] - mu) * rstd * gg[j] + bb[j];
  *(fv4*)(out + (size_t)row * DM_ + tid * 4) = o;
}

// ---------------------------------------------------------------------------
extern "C" void kernel_launch(void* const* d_in, const int* in_sizes, int n_in,
                              void* d_out, int out_size, void* d_ws, size_t ws_size,
                              hipStream_t stream) {
  const float* query = (const float*)d_in[0];
  const float* key   = (const float*)d_in[1];
  const float* value = (const float*)d_in[2];
  const int*   mask  = (const int*)d_in[3];
  const float* Wq = (const float*)d_in[4];
  const float* bq = (const float*)d_in[5];
  const float* Wk = (const float*)d_in[6];
  const float* bk = (const float*)d_in[7];
  const float* Wv = (const float*)d_in[8];
  const float* bv = (const float*)d_in[9];
  const float* Wo = (const float*)d_in[10];
  const float* bo = (const float*)d_in[11];
  const float* ln_g = (const float*)d_in[12];
  const float* ln_b = (const float*)d_in[13];

  float* out  = (float*)d_out;                       // [4096][1024]
  float* attn = out + (size_t)NTOK * DM_;            // [64][1024][1024]

  char* ws = (char*)d_ws;
  unsigned short* qb = (unsigned short*)ws;                   // 8 MB (q, prescaled)
  unsigned short* kb = qb + (size_t)NTOK * DM_;               // 8 MB
  unsigned short* vT = kb + (size_t)NTOK * DM_;               // 8 MB (transposed V)
  unsigned short* Ob = vT + (size_t)NTOK * DM_;               // 8 MB
  float* preln = (float*)ws;  // 16 MB, overlays qb+kb (dead after k_attn)

  k_proj<<<dim3(32, 8, 3), 256, 0, stream>>>(query, key, value, Wq, Wk, Wv,
                                             bq, bk, bv, qb, kb, vT);
  k_attn<<<dim3(64, 64), 256, 0, stream>>>(qb, kb, mask, attn);
  k_pv<<<dim3(8, 64), 256, 0, stream>>>(attn, vT, Ob);
  k_oproj<<<dim3(32, 8), 256, 0, stream>>>(Ob, Wo, bo, query, preln);
  k_ln<<<4096, 256, 0, stream>>>(preln, ln_g, ln_b, out);
}

// Round 3
// 631.520 us; speedup vs baseline: 1.0798x; 1.0798x over previous
//
#include <hip/hip_runtime.h>
#include <hip/hip_bf16.h>

typedef __attribute__((ext_vector_type(4))) float f32x4;
typedef __attribute__((ext_vector_type(4))) float fv4;
typedef __attribute__((ext_vector_type(8))) short bf16x8;
typedef __attribute__((ext_vector_type(4))) short bf16x4;

#define DEVI __device__ __forceinline__

constexpr int BATCH = 4, SEQ = 1024, NH = 16, HD = 64, DM_ = 1024;
constexpr int NTOK = BATCH * SEQ;  // 4096

DEVI unsigned short f2bf(float f) {
  union { float f; unsigned u; } v; v.f = f;
  unsigned r = v.u + 0x7FFFu + ((v.u >> 16) & 1u);  // RNE
  return (unsigned short)(r >> 16);
}

// XOR-swizzled element offset within a [rows][64] bf16 LDS tile (16B granules).
DEVI int swz64(int row, int col) {
  int byte = (row * 64 + col) * 2;
  byte ^= (row & 7) << 4;
  return byte >> 1;
}

// ---------------------------------------------------------------------------
// K1: fused QKV projection.  Y = X @ W^T + b, output bf16.
//   z=0: q (prescaled by 1/8), z=1: k, z=2: v stored transposed [b*1024+o][s]
// ---------------------------------------------------------------------------
__global__ __launch_bounds__(256) void k_proj(
    const float* __restrict__ Xq, const float* __restrict__ Xk,
    const float* __restrict__ Xv,
    const float* __restrict__ Wq, const float* __restrict__ Wk,
    const float* __restrict__ Wv,
    const float* __restrict__ bq, const float* __restrict__ bk,
    const float* __restrict__ bv,
    unsigned short* __restrict__ qo, unsigned short* __restrict__ ko,
    unsigned short* __restrict__ vTo)
{
  const int z = blockIdx.z;
  const float* X = (z == 0) ? Xq : (z == 1) ? Xk : Xv;
  const float* W = (z == 0) ? Wq : (z == 1) ? Wk : Wv;
  const float* bias = (z == 0) ? bq : (z == 1) ? bk : bv;

  __shared__ __align__(16) unsigned short Al[128 * 64];
  __shared__ __align__(16) unsigned short Bl[128 * 64];

  const int tid = threadIdx.x;
  const int lane = tid & 63;
  const int w = tid >> 6;
  const int wm = w & 1, wn = w >> 1;
  const int l15 = lane & 15, lg = lane >> 4;
  const int m0 = blockIdx.x * 128;  // token rows
  const int o0 = blockIdx.y * 128;  // output cols

  f32x4 acc[4][4];
#pragma unroll
  for (int i = 0; i < 4; ++i)
#pragma unroll
    for (int j = 0; j < 4; ++j) acc[i][j] = f32x4{0.f, 0.f, 0.f, 0.f};

  const int srow = tid >> 3;        // 0..31
  const int scol = (tid & 7) * 8;   // 0..56

  for (int kt = 0; kt < 16; ++kt) {
    const int k0 = kt * 64;
    __syncthreads();
#pragma unroll
    for (int p = 0; p < 4; ++p) {
      const int r = p * 32 + srow;
      {
        const float* sa = X + (size_t)(m0 + r) * DM_ + k0 + scol;
        fv4 a0 = *(const fv4*)sa;
        fv4 a1 = *(const fv4*)(sa + 4);
        bf16x8 ha;
        ha[0] = (short)f2bf(a0[0]); ha[1] = (short)f2bf(a0[1]);
        ha[2] = (short)f2bf(a0[2]); ha[3] = (short)f2bf(a0[3]);
        ha[4] = (short)f2bf(a1[0]); ha[5] = (short)f2bf(a1[1]);
        ha[6] = (short)f2bf(a1[2]); ha[7] = (short)f2bf(a1[3]);
        *(bf16x8*)&Al[swz64(r, scol)] = ha;
      }
      {
        const float* sb = W + (size_t)(o0 + r) * DM_ + k0 + scol;
        fv4 b0 = *(const fv4*)sb;
        fv4 b1 = *(const fv4*)(sb + 4);
        bf16x8 hb;
        hb[0] = (short)f2bf(b0[0]); hb[1] = (short)f2bf(b0[1]);
        hb[2] = (short)f2bf(b0[2]); hb[3] = (short)f2bf(b0[3]);
        hb[4] = (short)f2bf(b1[0]); hb[5] = (short)f2bf(b1[1]);
        hb[6] = (short)f2bf(b1[2]); hb[7] = (short)f2bf(b1[3]);
        *(bf16x8*)&Bl[swz64(r, scol)] = hb;
      }
    }
    __syncthreads();
#pragma unroll
    for (int kk = 0; kk < 2; ++kk) {
      bf16x8 af[4], bfm[4];
#pragma unroll
      for (int m = 0; m < 4; ++m)
        af[m] = *(const bf16x8*)&Al[swz64(wm * 64 + m * 16 + l15, kk * 32 + lg * 8)];
#pragma unroll
      for (int n = 0; n < 4; ++n)
        bfm[n] = *(const bf16x8*)&Bl[swz64(wn * 64 + n * 16 + l15, kk * 32 + lg * 8)];
#pragma unroll
      for (int m = 0; m < 4; ++m)
#pragma unroll
        for (int n = 0; n < 4; ++n)
          acc[m][n] = __builtin_amdgcn_mfma_f32_16x16x32_bf16(af[m], bfm[n], acc[m][n], 0, 0, 0);
    }
  }

#pragma unroll
  for (int n = 0; n < 4; ++n) {
    const int oc = o0 + wn * 64 + n * 16 + l15;
    const float bb = bias[oc];
#pragma unroll
    for (int m = 0; m < 4; ++m) {
      const int rbase = m0 + wm * 64 + m * 16 + lg * 4;
      if (z == 2) {
        bf16x4 pv;
#pragma unroll
        for (int j = 0; j < 4; ++j) pv[j] = (short)f2bf(acc[m][n][j] + bb);
        // vT[(b*1024 + o)][s], 4 consecutive s per lane
        *(bf16x4*)&vTo[((size_t)(rbase >> 10) * 1024 + oc) * 1024 + (rbase & 1023)] = pv;
      } else {
        unsigned short* Y = (z == 0) ? qo : ko;
        const float sc = (z == 0) ? 0.125f : 1.f;  // fold 1/sqrt(DK) into q
#pragma unroll
        for (int j = 0; j < 4; ++j)
          Y[(size_t)(rbase + j) * DM_ + oc] = f2bf((acc[m][n][j] + bb) * sc);
      }
    }
  }
}

// ---------------------------------------------------------------------------
// K2: fused scores + mask + softmax + PV.
//   Block = 16 q-rows x full 1024 k, one (h,b). 4 waves, wave w owns the
//   contiguous k-slice [w*256, w*256+256).
//   Swapped QK^T: C = mfma(K, Q) -> lane holds P[k=lg*4+j][q=l15]; per-lane
//   k-contiguous j => float4 attn stores + bf16x4 LDS P writes; softmax
//   reductions are scalar per lane.
//   PV: O^T = mfma(V^T, P^T) with P read back from LDS as the B fragment.
//   attn output gets normalized p*rinv; PV uses unnormalized bf16 p and
//   scales O by rinv (f32) in the epilogue. Causal tiles are skipped.
// ---------------------------------------------------------------------------
__global__ __launch_bounds__(256) void k_attn_pv(
    const unsigned short* __restrict__ qb, const unsigned short* __restrict__ kb,
    const unsigned short* __restrict__ vT, const int* __restrict__ mask,
    float* __restrict__ attn, unsigned short* __restrict__ Ob)
{
  const int tid = threadIdx.x;
  const int lane = tid & 63;
  const int w = tid >> 6;
  const int l15 = lane & 15, lg = lane >> 4;
  const int hb = blockIdx.y;
  const int h = hb >> 2, b = hb & 3;
  const int q0 = blockIdx.x * 16;
  const int qglob = q0 + l15;

  __shared__ __align__(16) unsigned short Pl[16 * 1024];  // 32KB [q][k], swizzled
  __shared__ float red[4][16];

  // Q fragment (B operand): lane l15 = q, lg*8 = d-group
  const unsigned short* qp = qb + (size_t)(b * SEQ + qglob) * DM_ + h * HD + lg * 8;
  const bf16x8 qf0 = *(const bf16x8*)qp;
  const bf16x8 qf1 = *(const bf16x8*)(qp + 32);

  const int qm = mask[b * SEQ + qglob];

  // causal limit: tiles with base > q0+15 are fully future
  const int rel = q0 + 15 - w * 256;
  const int f_lim = (rel < 0) ? 0 : ((rel / 16 + 1 > 16) ? 16 : rel / 16 + 1);

  f32x4 acc[16];
#pragma unroll
  for (int f = 0; f < 16; ++f) acc[f] = f32x4{0.f, 0.f, 0.f, 0.f};

  // QK^T (A = K rows: lane l15 = k-row)
#pragma unroll
  for (int f = 0; f < 16; ++f) {
    if (f < f_lim) {
      const int krow = w * 256 + f * 16 + l15;
      const unsigned short* kp = kb + (size_t)(b * SEQ + krow) * DM_ + h * HD + lg * 8;
      bf16x8 kf0 = *(const bf16x8*)kp;
      bf16x8 kf1 = *(const bf16x8*)(kp + 32);
      acc[f] = __builtin_amdgcn_mfma_f32_16x16x32_bf16(kf0, qf0, acc[f], 0, 0, 0);
      acc[f] = __builtin_amdgcn_mfma_f32_16x16x32_bf16(kf1, qf1, acc[f], 0, 0, 0);
    }
  }

  // key-validity bits for this lane's (f, j) slots
  unsigned long long kv = 0;
#pragma unroll
  for (int f = 0; f < 16; ++f) {
    if (f < f_lim) {
      const int kbase = w * 256 + f * 16 + lg * 4;
      int4 mv = *(const int4*)&mask[b * SEQ + kbase];
      if (mv.x == 0) kv |= 1ull << (f * 4 + 0);
      if (mv.y == 0) kv |= 1ull << (f * 4 + 1);
      if (mv.z == 0) kv |= 1ull << (f * 4 + 2);
      if (mv.w == 0) kv |= 1ull << (f * 4 + 3);
    }
  }
  if (qm != 0) kv = 0;  // fully-masked query row -> all invalid

  // row max (per lane: q = l15)
  float m = -1e30f;
#pragma unroll
  for (int f = 0; f < 16; ++f) {
    if (f < f_lim) {
      const int kbase = w * 256 + f * 16 + lg * 4;
#pragma unroll
      for (int j = 0; j < 4; ++j)
        if (((kv >> (f * 4 + j)) & 1ull) && (kbase + j <= qglob))
          m = fmaxf(m, acc[f][j]);
    }
  }
  m = fmaxf(m, __shfl_xor(m, 16, 64));
  m = fmaxf(m, __shfl_xor(m, 32, 64));
  if (lane < 16) red[w][l15] = m;
  __syncthreads();
  m = fmaxf(fmaxf(red[0][l15], red[1][l15]), fmaxf(red[2][l15], red[3][l15]));
  __syncthreads();  // all waves done reading max before sum overwrite

  // exp + row sum (acc <- unnormalized p)
  float s = 0.f;
#pragma unroll
  for (int f = 0; f < 16; ++f) {
    if (f < f_lim) {
      const int kbase = w * 256 + f * 16 + lg * 4;
#pragma unroll
      for (int j = 0; j < 4; ++j) {
        const bool vld = ((kv >> (f * 4 + j)) & 1ull) && (kbase + j <= qglob);
        const float p = vld ? __expf(acc[f][j] - m) : 0.f;
        acc[f][j] = p;
        s += p;
      }
    }
  }
  s += __shfl_xor(s, 16, 64);
  s += __shfl_xor(s, 32, 64);
  if (lane < 16) red[w][l15] = s;
  __syncthreads();
  s = red[0][l15] + red[1][l15] + red[2][l15] + red[3][l15];
  const float rinv = (s > 0.f) ? (1.f / s) : 0.f;

  // store attn (normalized, float4) + write P (unnormalized bf16) to LDS
  float* ap = attn + (size_t)hb * SEQ * SEQ + (size_t)qglob * SEQ;
#pragma unroll
  for (int f = 0; f < 16; ++f) {
    const int kbase = w * 256 + f * 16 + lg * 4;
    fv4 st;
    bf16x4 pb;
#pragma unroll
    for (int j = 0; j < 4; ++j) {
      st[j] = acc[f][j] * rinv;
      pb[j] = (short)f2bf(acc[f][j]);
    }
    *(fv4*)&ap[kbase] = st;
    const int pbyte = ((l15 * 1024 + kbase) * 2) ^ ((l15 & 7) << 4);
    *(bf16x4*)((char*)Pl + pbyte) = pb;
  }
  __syncthreads();

  // PV: O^T = mfma(V^T, P^T). Wave w owns d-tile [w*16, w*16+16).
  const int kt_lim = q0 / 32 + 1;  // covers all k <= q0+15 (P is zero beyond)
  f32x4 o = f32x4{0.f, 0.f, 0.f, 0.f};
  const unsigned short* vp = vT + (size_t)(b * 1024 + h * HD + w * 16 + l15) * 1024;
#pragma unroll 4
  for (int kt = 0; kt < kt_lim; ++kt) {
    const int k0 = kt * 32 + lg * 8;
    bf16x8 vf = *(const bf16x8*)(vp + k0);
    const int pbyte = ((l15 * 1024 + k0) * 2) ^ ((l15 & 7) << 4);
    bf16x8 pf = *(const bf16x8*)((const char*)Pl + pbyte);
    o = __builtin_amdgcn_mfma_f32_16x16x32_bf16(vf, pf, o, 0, 0, 0);
  }

  // epilogue: lane holds O[d=lg*4+j][q=l15]; scale by rinv (keyed by l15=q)
  bf16x4 ob;
#pragma unroll
  for (int j = 0; j < 4; ++j) ob[j] = (short)f2bf(o[j] * rinv);
  *(bf16x4*)&Ob[(size_t)(b * SEQ + qglob) * DM_ + h * HD + w * 16 + lg * 4] = ob;
}

// ---------------------------------------------------------------------------
// K4: preLN = O @ Wo^T + bo + query   (residual folded in epilogue)
// ---------------------------------------------------------------------------
__global__ __launch_bounds__(256) void k_oproj(
    const unsigned short* __restrict__ Ob, const float* __restrict__ Wo,
    const float* __restrict__ bo, const float* __restrict__ query,
    float* __restrict__ preln)
{
  const int tid = threadIdx.x;
  const int lane = tid & 63;
  const int w = tid >> 6;
  const int wm = w & 1, wn = w >> 1;
  const int l15 = lane & 15, lg = lane >> 4;
  const int m0 = blockIdx.x * 128;
  const int o0 = blockIdx.y * 128;

  __shared__ __align__(16) unsigned short Al[128 * 64];
  __shared__ __align__(16) unsigned short Bl[128 * 64];

  f32x4 acc[4][4];
#pragma unroll
  for (int i = 0; i < 4; ++i)
#pragma unroll
    for (int j = 0; j < 4; ++j) acc[i][j] = f32x4{0.f, 0.f, 0.f, 0.f};

  const int arow = tid >> 2, acol = (tid & 3) * 16;
  const int brow = tid >> 3, bcol = (tid & 7) * 8;

  for (int kt = 0; kt < 16; ++kt) {
    const int k0 = kt * 64;
    __syncthreads();
#pragma unroll
    for (int p = 0; p < 2; ++p) {
      const int r = p * 64 + arow;
      const unsigned short* src = Ob + (size_t)(m0 + r) * DM_ + k0 + acol;
      *(bf16x8*)&Al[swz64(r, acol)] = *(const bf16x8*)src;
      *(bf16x8*)&Al[swz64(r, acol + 8)] = *(const bf16x8*)(src + 8);
    }
#pragma unroll
    for (int p = 0; p < 4; ++p) {
      const int r = p * 32 + brow;
      const float* sb = Wo + (size_t)(o0 + r) * DM_ + k0 + bcol;
      fv4 b0 = *(const fv4*)sb;
      fv4 b1 = *(const fv4*)(sb + 4);
      bf16x8 hb;
      hb[0] = (short)f2bf(b0[0]); hb[1] = (short)f2bf(b0[1]);
      hb[2] = (short)f2bf(b0[2]); hb[3] = (short)f2bf(b0[3]);
      hb[4] = (short)f2bf(b1[0]); hb[5] = (short)f2bf(b1[1]);
      hb[6] = (short)f2bf(b1[2]); hb[7] = (short)f2bf(b1[3]);
      *(bf16x8*)&Bl[swz64(r, bcol)] = hb;
    }
    __syncthreads();
#pragma unroll
    for (int kk = 0; kk < 2; ++kk) {
      bf16x8 af[4], bfm[4];
#pragma unroll
      for (int m = 0; m < 4; ++m)
        af[m] = *(const bf16x8*)&Al[swz64(wm * 64 + m * 16 + l15, kk * 32 + lg * 8)];
#pragma unroll
      for (int n = 0; n < 4; ++n)
        bfm[n] = *(const bf16x8*)&Bl[swz64(wn * 64 + n * 16 + l15, kk * 32 + lg * 8)];
#pragma unroll
      for (int m = 0; m < 4; ++m)
#pragma unroll
        for (int n = 0; n < 4; ++n)
          acc[m][n] = __builtin_amdgcn_mfma_f32_16x16x32_bf16(af[m], bfm[n], acc[m][n], 0, 0, 0);
    }
  }

#pragma unroll
  for (int n = 0; n < 4; ++n) {
    const int oc = o0 + wn * 64 + n * 16 + l15;
    const float bb = bo[oc];
#pragma unroll
    for (int m = 0; m < 4; ++m) {
      const int rbase = m0 + wm * 64 + m * 16 + lg * 4;
#pragma unroll
      for (int j = 0; j < 4; ++j) {
        const size_t idx = (size_t)(rbase + j) * DM_ + oc;
        preln[idx] = acc[m][n][j] + bb + query[idx];
      }
    }
  }
}

// ---------------------------------------------------------------------------
// K5: LayerNorm over DM=1024, one block per row.
// ---------------------------------------------------------------------------
__global__ __launch_bounds__(256) void k_ln(
    const float* __restrict__ x, const float* __restrict__ g,
    const float* __restrict__ bta, float* __restrict__ out)
{
  const int row = blockIdx.x;
  const int tid = threadIdx.x;
  const float* xr = x + (size_t)row * DM_;
  fv4 v = *(const fv4*)(xr + tid * 4);
  float s = v[0] + v[1] + v[2] + v[3];
  float s2 = v[0] * v[0] + v[1] * v[1] + v[2] * v[2] + v[3] * v[3];
#pragma unroll
  for (int off = 1; off < 64; off <<= 1) {
    s += __shfl_xor(s, off, 64);
    s2 += __shfl_xor(s2, off, 64);
  }
  __shared__ float rs[2][4];
  const int w = tid >> 6;
  if ((tid & 63) == 0) { rs[0][w] = s; rs[1][w] = s2; }
  __syncthreads();
  s = rs[0][0] + rs[0][1] + rs[0][2] + rs[0][3];
  s2 = rs[1][0] + rs[1][1] + rs[1][2] + rs[1][3];
  const float mu = s * (1.f / 1024.f);
  const float var = s2 * (1.f / 1024.f) - mu * mu;
  const float rstd = rsqrtf(var + 1e-12f);
  fv4 gg = *(const fv4*)(g + tid * 4);
  fv4 bb = *(const fv4*)(bta + tid * 4);
  fv4 o;
#pragma unroll
  for (int j = 0; j < 4; ++j) o[j] = (v[j] - mu) * rstd * gg[j] + bb[j];
  *(fv4*)(out + (size_t)row * DM_ + tid * 4) = o;
}

// ---------------------------------------------------------------------------
extern "C" void kernel_launch(void* const* d_in, const int* in_sizes, int n_in,
                              void* d_out, int out_size, void* d_ws, size_t ws_size,
                              hipStream_t stream) {
  const float* query = (const float*)d_in[0];
  const float* key   = (const float*)d_in[1];
  const float* value = (const float*)d_in[2];
  const int*   mask  = (const int*)d_in[3];
  const float* Wq = (const float*)d_in[4];
  const float* bq = (const float*)d_in[5];
  const float* Wk = (const float*)d_in[6];
  const float* bk = (const float*)d_in[7];
  const float* Wv = (const float*)d_in[8];
  const float* bv = (const float*)d_in[9];
  const float* Wo = (const float*)d_in[10];
  const float* bo = (const float*)d_in[11];
  const float* ln_g = (const float*)d_in[12];
  const float* ln_b = (const float*)d_in[13];

  float* out  = (float*)d_out;                       // [4096][1024]
  float* attn = out + (size_t)NTOK * DM_;            // [64][1024][1024]

  char* ws = (char*)d_ws;
  unsigned short* qb = (unsigned short*)ws;                   // 8 MB (q, prescaled)
  unsigned short* kb = qb + (size_t)NTOK * DM_;               // 8 MB
  unsigned short* vT = kb + (size_t)NTOK * DM_;               // 8 MB (transposed V)
  unsigned short* Ob = vT + (size_t)NTOK * DM_;               // 8 MB
  float* preln = (float*)ws;  // 16 MB, overlays qb+kb (dead after k_attn_pv)

  k_proj<<<dim3(32, 8, 3), 256, 0, stream>>>(query, key, value, Wq, Wk, Wv,
                                             bq, bk, bv, qb, kb, vT);
  k_attn_pv<<<dim3(64, 64), 256, 0, stream>>>(qb, kb, vT, mask, attn, Ob);
  k_oproj<<<dim3(32, 8), 256, 0, stream>>>(Ob, Wo, bo, query, preln);
  k_ln<<<4096, 256, 0, stream>>>(preln, ln_g, ln_b, out);
}

// Round 4
// 526.390 us; speedup vs baseline: 1.2955x; 1.1997x over previous
//
#include <hip/hip_runtime.h>
#include <hip/hip_bf16.h>

typedef __attribute__((ext_vector_type(4))) float f32x4;
typedef __attribute__((ext_vector_type(4))) float fv4;
typedef __attribute__((ext_vector_type(8))) short bf16x8;
typedef __attribute__((ext_vector_type(4))) short bf16x4;

#define DEVI __device__ __forceinline__

constexpr int BATCH = 4, SEQ = 1024, NH = 16, HD = 64, DM_ = 1024;
constexpr int NTOK = BATCH * SEQ;  // 4096

DEVI unsigned short f2bf(float f) {
  union { float f; unsigned u; } v; v.f = f;
  unsigned r = v.u + 0x7FFFu + ((v.u >> 16) & 1u);  // RNE
  return (unsigned short)(r >> 16);
}

// XOR-swizzled element offset within a [rows][64] bf16 LDS tile (16B granules).
// Content placed by gld_lds16 with source chunk ^= (row&7); read with same XOR.
DEVI int swz64(int row, int col) {
  int byte = (row * 64 + col) * 2;
  byte ^= (row & 7) << 4;
  return byte >> 1;
}

// async global->LDS, 16B per lane. lds dest must be wave-uniform base.
DEVI void gld_lds16(const unsigned short* g, unsigned short* l) {
  __builtin_amdgcn_global_load_lds(
      (const __attribute__((address_space(1))) unsigned int*)g,
      (__attribute__((address_space(3))) unsigned int*)l, 16, 0, 0);
}

// ---------------------------------------------------------------------------
// K0: convert f32 inputs to bf16 workspace copies.
//   y=0..2 : query/key/value -> Xb[z]  (4096x1024)
//   y=3..6 : Wq/Wk/Wv/Wo     -> Wb[z]  (1024x1024)
// ---------------------------------------------------------------------------
__global__ __launch_bounds__(256) void k_cvt(
    const float* __restrict__ q, const float* __restrict__ k,
    const float* __restrict__ v,
    const float* __restrict__ wq, const float* __restrict__ wk,
    const float* __restrict__ wv, const float* __restrict__ wo,
    unsigned short* __restrict__ Xb, unsigned short* __restrict__ Wb)
{
  const int a = blockIdx.y;
  const float* src;
  unsigned short* dst;
  int n;
  if (a < 3) {
    src = (a == 0) ? q : (a == 1) ? k : v;
    dst = Xb + (size_t)a * NTOK * DM_;
    n = NTOK * DM_;
  } else {
    src = (a == 3) ? wq : (a == 4) ? wk : (a == 5) ? wv : wo;
    dst = Wb + (size_t)(a - 3) * DM_ * DM_;
    n = DM_ * DM_;
  }
  const int idx = (blockIdx.x * 256 + threadIdx.x) * 8;
  if (idx >= n) return;
  fv4 v0 = *(const fv4*)(src + idx);
  fv4 v1 = *(const fv4*)(src + idx + 4);
  bf16x8 o;
  o[0] = (short)f2bf(v0[0]); o[1] = (short)f2bf(v0[1]);
  o[2] = (short)f2bf(v0[2]); o[3] = (short)f2bf(v0[3]);
  o[4] = (short)f2bf(v1[0]); o[5] = (short)f2bf(v1[1]);
  o[6] = (short)f2bf(v1[2]); o[7] = (short)f2bf(v1[3]);
  *(bf16x8*)(dst + idx) = o;
}

// ---------------------------------------------------------------------------
// K1: fused QKV projection (bf16 in via global_load_lds).  Y = X @ W^T + b.
//   z=0: q (prescaled by 1/8), z=1: k, z=2: v stored transposed [b*1024+o][s]
// ---------------------------------------------------------------------------
__global__ __launch_bounds__(256) void k_proj(
    const unsigned short* __restrict__ Xb, const unsigned short* __restrict__ Wb,
    const float* __restrict__ bq, const float* __restrict__ bk,
    const float* __restrict__ bv,
    unsigned short* __restrict__ qo, unsigned short* __restrict__ ko,
    unsigned short* __restrict__ vTo)
{
  const int z = blockIdx.z;
  const unsigned short* X = Xb + (size_t)z * NTOK * DM_;
  const unsigned short* W = Wb + (size_t)z * DM_ * DM_;
  const float* bias = (z == 0) ? bq : (z == 1) ? bk : bv;

  __shared__ __align__(16) unsigned short Al[128 * 64];
  __shared__ __align__(16) unsigned short Bl[128 * 64];

  const int tid = threadIdx.x;
  const int lane = tid & 63;
  const int w = tid >> 6;
  const int wm = w & 1, wn = w >> 1;
  const int l15 = lane & 15, lg = lane >> 4;
  const int m0 = blockIdx.x * 128;
  const int o0 = blockIdx.y * 128;

  const int rseg = lane >> 3;                 // 0..7 row within 8-row segment
  const int cg = (lane & 7) ^ rseg;           // pre-swizzled source chunk

  f32x4 acc[4][4];
#pragma unroll
  for (int i = 0; i < 4; ++i)
#pragma unroll
    for (int j = 0; j < 4; ++j) acc[i][j] = f32x4{0.f, 0.f, 0.f, 0.f};

  for (int kt = 0; kt < 16; ++kt) {
    const int k0 = kt * 64;
    __syncthreads();
#pragma unroll
    for (int i = 0; i < 4; ++i) {
      const int seg = w * 4 + i;
      const int row = seg * 8 + rseg;
      gld_lds16(X + (size_t)(m0 + row) * DM_ + k0 + cg * 8, &Al[seg * 512]);
      gld_lds16(W + (size_t)(o0 + row) * DM_ + k0 + cg * 8, &Bl[seg * 512]);
    }
    __syncthreads();
#pragma unroll
    for (int kk = 0; kk < 2; ++kk) {
      bf16x8 af[4], bfm[4];
#pragma unroll
      for (int m = 0; m < 4; ++m)
        af[m] = *(const bf16x8*)&Al[swz64(wm * 64 + m * 16 + l15, kk * 32 + lg * 8)];
#pragma unroll
      for (int n = 0; n < 4; ++n)
        bfm[n] = *(const bf16x8*)&Bl[swz64(wn * 64 + n * 16 + l15, kk * 32 + lg * 8)];
#pragma unroll
      for (int m = 0; m < 4; ++m)
#pragma unroll
        for (int n = 0; n < 4; ++n)
          acc[m][n] = __builtin_amdgcn_mfma_f32_16x16x32_bf16(af[m], bfm[n], acc[m][n], 0, 0, 0);
    }
  }

#pragma unroll
  for (int n = 0; n < 4; ++n) {
    const int oc = o0 + wn * 64 + n * 16 + l15;
    const float bb = bias[oc];
#pragma unroll
    for (int m = 0; m < 4; ++m) {
      const int rbase = m0 + wm * 64 + m * 16 + lg * 4;
      if (z == 2) {
        bf16x4 pv;
#pragma unroll
        for (int j = 0; j < 4; ++j) pv[j] = (short)f2bf(acc[m][n][j] + bb);
        *(bf16x4*)&vTo[((size_t)(rbase >> 10) * 1024 + oc) * 1024 + (rbase & 1023)] = pv;
      } else {
        unsigned short* Y = (z == 0) ? qo : ko;
        const float sc = (z == 0) ? 0.125f : 1.f;  // fold 1/sqrt(DK) into q
#pragma unroll
        for (int j = 0; j < 4; ++j)
          Y[(size_t)(rbase + j) * DM_ + oc] = f2bf((acc[m][n][j] + bb) * sc);
      }
    }
  }
}

// ---------------------------------------------------------------------------
// K2: fused scores + mask + softmax + PV, causal-balanced.
//   Block = 16 q-rows x full 1024 k, one (h,b). Wave w owns interleaved
//   16-wide k-tiles ftile = w + 4*i  (balanced under causality).
//   Swapped QK^T: lane holds P[k=lg*4+j][q=l15]. PV: O^T = mfma(V^T, P^T).
// ---------------------------------------------------------------------------
__global__ __launch_bounds__(256) void k_attn_pv(
    const unsigned short* __restrict__ qb, const unsigned short* __restrict__ kb,
    const unsigned short* __restrict__ vT, const int* __restrict__ mask,
    float* __restrict__ attn, unsigned short* __restrict__ Ob)
{
  const int tid = threadIdx.x;
  const int lane = tid & 63;
  const int w = tid >> 6;
  const int l15 = lane & 15, lg = lane >> 4;
  const int hb = blockIdx.y;
  const int h = hb >> 2, b = hb & 3;
  const int t = blockIdx.x;            // q-tile
  const int q0 = t * 16;
  const int qglob = q0 + l15;

  __shared__ __align__(16) unsigned short Pl[16 * 1024];  // 32KB [q][k] swizzled
  __shared__ float red[4][16];

  const unsigned short* qp = qb + (size_t)(b * SEQ + qglob) * DM_ + h * HD + lg * 8;
  const bf16x8 qf0 = *(const bf16x8*)qp;
  const bf16x8 qf1 = *(const bf16x8*)(qp + 32);

  const int qm = mask[b * SEQ + qglob];
  const int ni = (t >= w) ? (((t - w) >> 2) + 1) : 0;  // active tiles, <=16

  f32x4 acc[16];
#pragma unroll
  for (int i = 0; i < 16; ++i) acc[i] = f32x4{0.f, 0.f, 0.f, 0.f};

  // QK^T (A = K rows)
#pragma unroll
  for (int i = 0; i < 16; ++i) {
    if (i < ni) {
      const int krow = (w + 4 * i) * 16 + l15;
      const unsigned short* kp = kb + (size_t)(b * SEQ + krow) * DM_ + h * HD + lg * 8;
      bf16x8 kf0 = *(const bf16x8*)kp;
      bf16x8 kf1 = *(const bf16x8*)(kp + 32);
      acc[i] = __builtin_amdgcn_mfma_f32_16x16x32_bf16(kf0, qf0, acc[i], 0, 0, 0);
      acc[i] = __builtin_amdgcn_mfma_f32_16x16x32_bf16(kf1, qf1, acc[i], 0, 0, 0);
    }
  }

  // key-validity bits
  unsigned long long kv = 0;
#pragma unroll
  for (int i = 0; i < 16; ++i) {
    if (i < ni) {
      const int kbase = (w + 4 * i) * 16 + lg * 4;
      int4 mv = *(const int4*)&mask[b * SEQ + kbase];
      if (mv.x == 0) kv |= 1ull << (i * 4 + 0);
      if (mv.y == 0) kv |= 1ull << (i * 4 + 1);
      if (mv.z == 0) kv |= 1ull << (i * 4 + 2);
      if (mv.w == 0) kv |= 1ull << (i * 4 + 3);
    }
  }
  if (qm != 0) kv = 0;

  // row max
  float m = -1e30f;
#pragma unroll
  for (int i = 0; i < 16; ++i) {
    if (i < ni) {
      const int kbase = (w + 4 * i) * 16 + lg * 4;
#pragma unroll
      for (int j = 0; j < 4; ++j)
        if (((kv >> (i * 4 + j)) & 1ull) && (kbase + j <= qglob))
          m = fmaxf(m, acc[i][j]);
    }
  }
  m = fmaxf(m, __shfl_xor(m, 16, 64));
  m = fmaxf(m, __shfl_xor(m, 32, 64));
  if (lane < 16) red[w][l15] = m;
  __syncthreads();
  m = fmaxf(fmaxf(red[0][l15], red[1][l15]), fmaxf(red[2][l15], red[3][l15]));
  __syncthreads();

  // exp + row sum
  float s = 0.f;
#pragma unroll
  for (int i = 0; i < 16; ++i) {
    if (i < ni) {
      const int kbase = (w + 4 * i) * 16 + lg * 4;
#pragma unroll
      for (int j = 0; j < 4; ++j) {
        const bool vld = ((kv >> (i * 4 + j)) & 1ull) && (kbase + j <= qglob);
        const float p = vld ? __expf(acc[i][j] - m) : 0.f;
        acc[i][j] = p;
        s += p;
      }
    }
  }
  s += __shfl_xor(s, 16, 64);
  s += __shfl_xor(s, 32, 64);
  if (lane < 16) red[w][l15] = s;
  __syncthreads();
  s = red[0][l15] + red[1][l15] + red[2][l15] + red[3][l15];
  const float rinv = (s > 0.f) ? (1.f / s) : 0.f;

  // store attn (normalized f32x4) + P (unnormalized bf16) to LDS
  float* ap = attn + (size_t)hb * SEQ * SEQ + (size_t)qglob * SEQ;
#pragma unroll
  for (int i = 0; i < 16; ++i) {
    const int kbase = (w + 4 * i) * 16 + lg * 4;
    const int pbyte = ((l15 * 1024 + kbase) * 2) ^ ((l15 & 7) << 4);
    if (i < ni) {
      fv4 st;
      bf16x4 pb;
#pragma unroll
      for (int j = 0; j < 4; ++j) {
        st[j] = acc[i][j] * rinv;
        pb[j] = (short)f2bf(acc[i][j]);
      }
      *(fv4*)&ap[kbase] = st;
      *(bf16x4*)((char*)Pl + pbyte) = pb;
    } else {
      *(fv4*)&ap[kbase] = fv4{0.f, 0.f, 0.f, 0.f};
      *(bf16x4*)((char*)Pl + pbyte) = bf16x4{0, 0, 0, 0};
    }
  }
  __syncthreads();

  // PV: O^T = mfma(V^T, P^T). Wave w owns d-tile [w*16, w*16+16).
  const int kt_lim = (q0 >> 5) + 1;
  f32x4 o = f32x4{0.f, 0.f, 0.f, 0.f};
  const unsigned short* vp = vT + (size_t)(b * 1024 + h * HD + w * 16 + l15) * 1024;
#pragma unroll 4
  for (int kt = 0; kt < kt_lim; ++kt) {
    const int k0 = kt * 32 + lg * 8;
    bf16x8 vf = *(const bf16x8*)(vp + k0);
    const int pbyte = ((l15 * 1024 + k0) * 2) ^ ((l15 & 7) << 4);
    bf16x8 pf = *(const bf16x8*)((const char*)Pl + pbyte);
    o = __builtin_amdgcn_mfma_f32_16x16x32_bf16(vf, pf, o, 0, 0, 0);
  }

  bf16x4 ob;
#pragma unroll
  for (int j = 0; j < 4; ++j) ob[j] = (short)f2bf(o[j] * rinv);
  *(bf16x4*)&Ob[(size_t)(b * SEQ + qglob) * DM_ + h * HD + w * 16 + lg * 4] = ob;
}

// ---------------------------------------------------------------------------
// K4: preLN = O @ Wo^T + bo + query  (bf16 A/B via global_load_lds)
// ---------------------------------------------------------------------------
__global__ __launch_bounds__(256) void k_oproj(
    const unsigned short* __restrict__ Ob, const unsigned short* __restrict__ Wb,
    const float* __restrict__ bo, const float* __restrict__ query,
    float* __restrict__ preln)
{
  const unsigned short* W = Wb + (size_t)3 * DM_ * DM_;  // Wo_b

  __shared__ __align__(16) unsigned short Al[128 * 64];
  __shared__ __align__(16) unsigned short Bl[128 * 64];

  const int tid = threadIdx.x;
  const int lane = tid & 63;
  const int w = tid >> 6;
  const int wm = w & 1, wn = w >> 1;
  const int l15 = lane & 15, lg = lane >> 4;
  const int m0 = blockIdx.x * 128;
  const int o0 = blockIdx.y * 128;

  const int rseg = lane >> 3;
  const int cg = (lane & 7) ^ rseg;

  f32x4 acc[4][4];
#pragma unroll
  for (int i = 0; i < 4; ++i)
#pragma unroll
    for (int j = 0; j < 4; ++j) acc[i][j] = f32x4{0.f, 0.f, 0.f, 0.f};

  for (int kt = 0; kt < 16; ++kt) {
    const int k0 = kt * 64;
    __syncthreads();
#pragma unroll
    for (int i = 0; i < 4; ++i) {
      const int seg = w * 4 + i;
      const int row = seg * 8 + rseg;
      gld_lds16(Ob + (size_t)(m0 + row) * DM_ + k0 + cg * 8, &Al[seg * 512]);
      gld_lds16(W + (size_t)(o0 + row) * DM_ + k0 + cg * 8, &Bl[seg * 512]);
    }
    __syncthreads();
#pragma unroll
    for (int kk = 0; kk < 2; ++kk) {
      bf16x8 af[4], bfm[4];
#pragma unroll
      for (int m = 0; m < 4; ++m)
        af[m] = *(const bf16x8*)&Al[swz64(wm * 64 + m * 16 + l15, kk * 32 + lg * 8)];
#pragma unroll
      for (int n = 0; n < 4; ++n)
        bfm[n] = *(const bf16x8*)&Bl[swz64(wn * 64 + n * 16 + l15, kk * 32 + lg * 8)];
#pragma unroll
      for (int m = 0; m < 4; ++m)
#pragma unroll
        for (int n = 0; n < 4; ++n)
          acc[m][n] = __builtin_amdgcn_mfma_f32_16x16x32_bf16(af[m], bfm[n], acc[m][n], 0, 0, 0);
    }
  }

#pragma unroll
  for (int n = 0; n < 4; ++n) {
    const int oc = o0 + wn * 64 + n * 16 + l15;
    const float bb = bo[oc];
#pragma unroll
    for (int m = 0; m < 4; ++m) {
      const int rbase = m0 + wm * 64 + m * 16 + lg * 4;
#pragma unroll
      for (int j = 0; j < 4; ++j) {
        const size_t idx = (size_t)(rbase + j) * DM_ + oc;
        preln[idx] = acc[m][n][j] + bb + query[idx];
      }
    }
  }
}

// ---------------------------------------------------------------------------
// K5: LayerNorm over DM=1024, one block per row.
// ---------------------------------------------------------------------------
__global__ __launch_bounds__(256) void k_ln(
    const float* __restrict__ x, const float* __restrict__ g,
    const float* __restrict__ bta, float* __restrict__ out)
{
  const int row = blockIdx.x;
  const int tid = threadIdx.x;
  const float* xr = x + (size_t)row * DM_;
  fv4 v = *(const fv4*)(xr + tid * 4);
  float s = v[0] + v[1] + v[2] + v[3];
  float s2 = v[0] * v[0] + v[1] * v[1] + v[2] * v[2] + v[3] * v[3];
#pragma unroll
  for (int off = 1; off < 64; off <<= 1) {
    s += __shfl_xor(s, off, 64);
    s2 += __shfl_xor(s2, off, 64);
  }
  __shared__ float rs[2][4];
  const int w = tid >> 6;
  if ((tid & 63) == 0) { rs[0][w] = s; rs[1][w] = s2; }
  __syncthreads();
  s = rs[0][0] + rs[0][1] + rs[0][2] + rs[0][3];
  s2 = rs[1][0] + rs[1][1] + rs[1][2] + rs[1][3];
  const float mu = s * (1.f / 1024.f);
  const float var = s2 * (1.f / 1024.f) - mu * mu;
  const float rstd = rsqrtf(var + 1e-12f);
  fv4 gg = *(const fv4*)(g + tid * 4);
  fv4 bb = *(const fv4*)(bta + tid * 4);
  fv4 o;
#pragma unroll
  for (int j = 0; j < 4; ++j) o[j] = (v[j] - mu) * rstd * gg[j] + bb[j];
  *(fv4*)(out + (size_t)row * DM_ + tid * 4) = o;
}

// ---------------------------------------------------------------------------
extern "C" void kernel_launch(void* const* d_in, const int* in_sizes, int n_in,
                              void* d_out, int out_size, void* d_ws, size_t ws_size,
                              hipStream_t stream) {
  const float* query = (const float*)d_in[0];
  const float* key   = (const float*)d_in[1];
  const float* value = (const float*)d_in[2];
  const int*   mask  = (const int*)d_in[3];
  const float* Wq = (const float*)d_in[4];
  const float* bq = (const float*)d_in[5];
  const float* Wk = (const float*)d_in[6];
  const float* bk = (const float*)d_in[7];
  const float* Wv = (const float*)d_in[8];
  const float* bv = (const float*)d_in[9];
  const float* Wo = (const float*)d_in[10];
  const float* bo = (const float*)d_in[11];
  const float* ln_g = (const float*)d_in[12];
  const float* ln_b = (const float*)d_in[13];

  float* out  = (float*)d_out;                       // [4096][1024]
  float* attn = out + (size_t)NTOK * DM_;            // [64][1024][1024]

  char* ws = (char*)d_ws;
  unsigned short* Xb = (unsigned short*)ws;                    // 24 MB (3x X bf16)
  unsigned short* Wb = Xb + (size_t)3 * NTOK * DM_;            // 8 MB  (4x W bf16)
  unsigned short* qb = Wb + (size_t)4 * DM_ * DM_;             // 8 MB (q prescaled)
  unsigned short* kb = qb + (size_t)NTOK * DM_;                // 8 MB
  unsigned short* vT = kb + (size_t)NTOK * DM_;                // 8 MB
  unsigned short* Ob = vT + (size_t)NTOK * DM_;                // 8 MB
  float* preln = (float*)ws;  // 16 MB, overlays Xb (dead after k_proj)

  k_cvt<<<dim3(2048, 7), 256, 0, stream>>>(query, key, value, Wq, Wk, Wv, Wo,
                                           Xb, Wb);
  k_proj<<<dim3(32, 8, 3), 256, 0, stream>>>(Xb, Wb, bq, bk, bv, qb, kb, vT);
  k_attn_pv<<<dim3(64, 64), 256, 0, stream>>>(qb, kb, vT, mask, attn, Ob);
  k_oproj<<<dim3(32, 8), 256, 0, stream>>>(Ob, Wb, bo, query, preln);
  k_ln<<<4096, 256, 0, stream>>>(preln, ln_g, ln_b, out);
}